// Round 3
// baseline (347.741 us; speedup 1.0000x reference)
//
#include <hip/hip_runtime.h>

// EquivariantLayerNorm: per row n (65536 rows), x = in[n] (3x256 fp32),
//   mean-center over D; B = x x^T / D + EPS*diag(2,3,4); out = B^{-1/2} x_c * w.
// B^{-1/2} via trace-normalized coupled Newton-Schulz (8 iters, fp32).
//
// R5: R3's layout (32 lanes/row, 8 rows per 256-block, fully coalesced 512 B
// segments, nontemporal touch-once streams) + de-redundant Newton-Schulz.
// R4 showed NS cost is per-WAVE: every lane redundantly computing its row's
// NS means a wave's ~480-instr chain serves only (64/lanes_per_row) rows.
// R5 restructures: phase 1 reduces Gram per 32-lane group -> LDS (9 floats);
// phase 2 has 8 threads (one per row) run the NS chain once; phase 3
// broadcast-reads {m, M} and applies the transform. Chip-wide NS VALU drops
// ~4x vs R3 (12.8 -> ~3 us), exposing the HBM floor.

namespace {

constexpr int kD = 256;
constexpr float kEps = 1e-3f;
constexpr int kNSIters = 8;
constexpr int kRowsPerBlock = 8;     // 256 threads / 32 lanes per row

typedef float f4 __attribute__((ext_vector_type(4)));

// Symmetric 3x3 stored as {a00,a01,a02,a11,a12,a22}. P = M*N upper triangle
// (M,N commute up to rounding, so P is symmetric to fp32 noise).
__device__ __forceinline__ void symmul(const float* M, const float* N, float* P) {
    P[0] = M[0]*N[0] + M[1]*N[1] + M[2]*N[2];
    P[1] = M[0]*N[1] + M[1]*N[3] + M[2]*N[4];
    P[2] = M[0]*N[2] + M[1]*N[4] + M[2]*N[5];
    P[3] = M[1]*N[1] + M[3]*N[3] + M[4]*N[4];
    P[4] = M[1]*N[2] + M[3]*N[4] + M[4]*N[5];
    P[5] = M[2]*N[2] + M[4]*N[4] + M[5]*N[5];
}

__global__ __launch_bounds__(256, 8) void eqln_kernel(const float* __restrict__ in,
                                                      const float* __restrict__ wptr,
                                                      float* __restrict__ out,
                                                      int nrows) {
    const int tid     = threadIdx.x;
    const int lane_in = tid & 31;                        // lane within row-group
    const int grp     = tid >> 5;                        // 0..7, row within block
    const int row     = blockIdx.x * kRowsPerBlock + grp;

    // {m0,m1,m2, B0..B5} per row in phase 1; overwritten with
    // {m0,m1,m2, M00,M01,M02,M11,M12,M22} in phase 2. Stride 12 floats ->
    // 8 writer lanes hit 8 distinct banks; phase-3 reads are broadcast.
    __shared__ float sm[kRowsPerBlock][12];

    const bool valid = row < nrows;
    const size_t base = (size_t)row * (3 * kD);
    const int coff = lane_in * 4;                        // + j*128 per block j

    // ---- Phase 1: load + Gram partials + 32-lane butterfly ----
    f4 x[3][2];
    float s[9] = {0.f, 0.f, 0.f, 0.f, 0.f, 0.f, 0.f, 0.f, 0.f};
    if (valid) {
        #pragma unroll
        for (int v = 0; v < 3; ++v)
            #pragma unroll
            for (int j = 0; j < 2; ++j)
                x[v][j] = __builtin_nontemporal_load(
                    (const f4*)(in + base + v * kD + j * 128 + coff));

        #pragma unroll
        for (int j = 0; j < 2; ++j) {
            const f4 a = x[0][j];
            const f4 b = x[1][j];
            const f4 c = x[2][j];
            #pragma unroll
            for (int k = 0; k < 4; ++k) {
                s[0] += a[k];      s[1] += b[k];      s[2] += c[k];
                s[3] += a[k]*a[k]; s[4] += a[k]*b[k]; s[5] += a[k]*c[k];
                s[6] += b[k]*b[k]; s[7] += b[k]*c[k]; s[8] += c[k]*c[k];
            }
        }

        #pragma unroll
        for (int off = 16; off > 0; off >>= 1) {
            #pragma unroll
            for (int i = 0; i < 9; ++i) s[i] += __shfl_xor(s[i], off, 64);
        }

        if (lane_in == 0) {
            const float inv_d = 1.0f / (float)kD;
            const float m0 = s[0] * inv_d, m1 = s[1] * inv_d, m2 = s[2] * inv_d;
            sm[grp][0] = m0;
            sm[grp][1] = m1;
            sm[grp][2] = m2;
            sm[grp][3] = s[3] * inv_d - m0 * m0 + 2.0f * kEps;
            sm[grp][4] = s[4] * inv_d - m0 * m1;
            sm[grp][5] = s[5] * inv_d - m0 * m2;
            sm[grp][6] = s[6] * inv_d - m1 * m1 + 3.0f * kEps;
            sm[grp][7] = s[7] * inv_d - m1 * m2;
            sm[grp][8] = s[8] * inv_d - m2 * m2 + 4.0f * kEps;
        }
    }
    __syncthreads();

    // ---- Phase 2: one thread per row runs the Newton-Schulz chain once ----
    if (tid < kRowsPerBlock && (blockIdx.x * kRowsPerBlock + tid) < nrows) {
        float B[6];
        #pragma unroll
        for (int i = 0; i < 6; ++i) B[i] = sm[tid][3 + i];

        const float tr  = B[0] + B[3] + B[5];
        const float itr = 1.0f / tr;
        float Y[6] = {B[0]*itr, B[1]*itr, B[2]*itr, B[3]*itr, B[4]*itr, B[5]*itr};
        float Z[6] = {1.0f, 0.0f, 0.0f, 1.0f, 0.0f, 1.0f};

        #pragma unroll
        for (int it = 0; it < kNSIters; ++it) {
            float W[6], T[6], Yn[6], Zn[6];
            symmul(Z, Y, W);
            T[0] = 1.5f - 0.5f * W[0];
            T[1] = -0.5f * W[1];
            T[2] = -0.5f * W[2];
            T[3] = 1.5f - 0.5f * W[3];
            T[4] = -0.5f * W[4];
            T[5] = 1.5f - 0.5f * W[5];
            symmul(Y, T, Yn);
            symmul(T, Z, Zn);
            #pragma unroll
            for (int i = 0; i < 6; ++i) { Y[i] = Yn[i]; Z[i] = Zn[i]; }
        }

        const float sc = 1.0f / sqrtf(tr);        // B^{-1/2} = Z / sqrt(tr)
        #pragma unroll
        for (int i = 0; i < 6; ++i) sm[tid][3 + i] = Z[i] * sc;
    }
    __syncthreads();

    // ---- Phase 3: broadcast {m, M}, transform, store ----
    if (valid) {
        const float m0  = sm[grp][0], m1 = sm[grp][1], m2 = sm[grp][2];
        const float M00 = sm[grp][3], M01 = sm[grp][4], M02 = sm[grp][5];
        const float M11 = sm[grp][6], M12 = sm[grp][7], M22 = sm[grp][8];

        #pragma unroll
        for (int j = 0; j < 2; ++j) {
            const f4 wv = *(const f4*)(wptr + j * 128 + coff);
            const f4 a  = x[0][j];
            const f4 b  = x[1][j];
            const f4 c  = x[2][j];
            f4 r0, r1, r2;
            #pragma unroll
            for (int k = 0; k < 4; ++k) {
                const float a0 = a[k] - m0;
                const float a1 = b[k] - m1;
                const float a2 = c[k] - m2;
                r0[k] = (M00 * a0 + M01 * a1 + M02 * a2) * wv[k];
                r1[k] = (M01 * a0 + M11 * a1 + M12 * a2) * wv[k];
                r2[k] = (M02 * a0 + M12 * a1 + M22 * a2) * wv[k];
            }
            __builtin_nontemporal_store(r0, (f4*)(out + base + 0 * kD + j * 128 + coff));
            __builtin_nontemporal_store(r1, (f4*)(out + base + 1 * kD + j * 128 + coff));
            __builtin_nontemporal_store(r2, (f4*)(out + base + 2 * kD + j * 128 + coff));
        }
    }
}

}  // namespace

extern "C" void kernel_launch(void* const* d_in, const int* in_sizes, int n_in,
                              void* d_out, int out_size, void* d_ws, size_t ws_size,
                              hipStream_t stream) {
    (void)n_in; (void)d_ws; (void)ws_size; (void)out_size;
    const float* in   = (const float*)d_in[0];
    const float* wght = (const float*)d_in[1];
    float* out = (float*)d_out;

    const int nrows = in_sizes[0] / (3 * kD);      // 65536
    const int blocks = (nrows + kRowsPerBlock - 1) / kRowsPerBlock;

    eqln_kernel<<<blocks, 256, 0, stream>>>(in, wght, out, nrows);
}

// Round 4
// 319.355 us; speedup vs baseline: 1.0889x; 1.0889x over previous
//
#include <hip/hip_runtime.h>

// EquivariantLayerNorm: per row n (65536 rows), x = in[n] (3x256 fp32),
//   mean-center over D; B = x x^T / D + EPS*diag(2,3,4); out = B^{-1/2} x_c * w.
// B^{-1/2} via trace-normalized coupled Newton-Schulz (8 iters, fp32).
//
// R6 = R5's 3-phase structure WITHOUT the __launch_bounds__(256,8) VGPR cap.
// Evidence: R4 (64-lane redundant-NS) and R5 (32-lane LDS-phased NS) measured
// IDENTICAL (347.7 us) -- their only common difference vs the best kernel R3
// (319.0 us) was the min-waves=8 bound forcing VGPR<=64 (spills / constrained
// scheduling). R5 also proved de-redundant NS is perf-neutral (fully hidden),
// so keep the phased structure (fewer wave-instructions, no cost) and restore
// natural register allocation.
// Layout (R3, measured best): 32 lanes/row, 8 rows per 256-block; lane owns
// 8 columns via col = lane*4 + j*128 -> 512 B contiguous per access, fully
// coalesced. Nontemporal loads/stores: both 192 MiB streams are touch-once.

namespace {

constexpr int kD = 256;
constexpr float kEps = 1e-3f;
constexpr int kNSIters = 8;
constexpr int kRowsPerBlock = 8;     // 256 threads / 32 lanes per row

typedef float f4 __attribute__((ext_vector_type(4)));

// Symmetric 3x3 stored as {a00,a01,a02,a11,a12,a22}. P = M*N upper triangle
// (M,N commute up to rounding, so P is symmetric to fp32 noise).
__device__ __forceinline__ void symmul(const float* M, const float* N, float* P) {
    P[0] = M[0]*N[0] + M[1]*N[1] + M[2]*N[2];
    P[1] = M[0]*N[1] + M[1]*N[3] + M[2]*N[4];
    P[2] = M[0]*N[2] + M[1]*N[4] + M[2]*N[5];
    P[3] = M[1]*N[1] + M[3]*N[3] + M[4]*N[4];
    P[4] = M[1]*N[2] + M[3]*N[4] + M[4]*N[5];
    P[5] = M[2]*N[2] + M[4]*N[4] + M[5]*N[5];
}

__global__ __launch_bounds__(256) void eqln_kernel(const float* __restrict__ in,
                                                   const float* __restrict__ wptr,
                                                   float* __restrict__ out,
                                                   int nrows) {
    const int tid     = threadIdx.x;
    const int lane_in = tid & 31;                        // lane within row-group
    const int grp     = tid >> 5;                        // 0..7, row within block
    const int row     = blockIdx.x * kRowsPerBlock + grp;

    // {m0,m1,m2, B0..B5} per row in phase 1; overwritten with
    // {m0,m1,m2, M00,M01,M02,M11,M12,M22} in phase 2. Stride 12 floats ->
    // 8 writer lanes hit 8 distinct banks; phase-3 reads are broadcast.
    __shared__ float sm[kRowsPerBlock][12];

    const bool valid = row < nrows;
    const size_t base = (size_t)row * (3 * kD);
    const int coff = lane_in * 4;                        // + j*128 per block j

    // ---- Phase 1: load + Gram partials + 32-lane butterfly ----
    f4 x[3][2];
    float s[9] = {0.f, 0.f, 0.f, 0.f, 0.f, 0.f, 0.f, 0.f, 0.f};
    if (valid) {
        #pragma unroll
        for (int v = 0; v < 3; ++v)
            #pragma unroll
            for (int j = 0; j < 2; ++j)
                x[v][j] = __builtin_nontemporal_load(
                    (const f4*)(in + base + v * kD + j * 128 + coff));

        #pragma unroll
        for (int j = 0; j < 2; ++j) {
            const f4 a = x[0][j];
            const f4 b = x[1][j];
            const f4 c = x[2][j];
            #pragma unroll
            for (int k = 0; k < 4; ++k) {
                s[0] += a[k];      s[1] += b[k];      s[2] += c[k];
                s[3] += a[k]*a[k]; s[4] += a[k]*b[k]; s[5] += a[k]*c[k];
                s[6] += b[k]*b[k]; s[7] += b[k]*c[k]; s[8] += c[k]*c[k];
            }
        }

        #pragma unroll
        for (int off = 16; off > 0; off >>= 1) {
            #pragma unroll
            for (int i = 0; i < 9; ++i) s[i] += __shfl_xor(s[i], off, 64);
        }

        if (lane_in == 0) {
            const float inv_d = 1.0f / (float)kD;
            const float m0 = s[0] * inv_d, m1 = s[1] * inv_d, m2 = s[2] * inv_d;
            sm[grp][0] = m0;
            sm[grp][1] = m1;
            sm[grp][2] = m2;
            sm[grp][3] = s[3] * inv_d - m0 * m0 + 2.0f * kEps;
            sm[grp][4] = s[4] * inv_d - m0 * m1;
            sm[grp][5] = s[5] * inv_d - m0 * m2;
            sm[grp][6] = s[6] * inv_d - m1 * m1 + 3.0f * kEps;
            sm[grp][7] = s[7] * inv_d - m1 * m2;
            sm[grp][8] = s[8] * inv_d - m2 * m2 + 4.0f * kEps;
        }
    }
    __syncthreads();

    // ---- Phase 2: one thread per row runs the Newton-Schulz chain once ----
    if (tid < kRowsPerBlock && (blockIdx.x * kRowsPerBlock + tid) < nrows) {
        float B[6];
        #pragma unroll
        for (int i = 0; i < 6; ++i) B[i] = sm[tid][3 + i];

        const float tr  = B[0] + B[3] + B[5];
        const float itr = 1.0f / tr;
        float Y[6] = {B[0]*itr, B[1]*itr, B[2]*itr, B[3]*itr, B[4]*itr, B[5]*itr};
        float Z[6] = {1.0f, 0.0f, 0.0f, 1.0f, 0.0f, 1.0f};

        #pragma unroll
        for (int it = 0; it < kNSIters; ++it) {
            float W[6], T[6], Yn[6], Zn[6];
            symmul(Z, Y, W);
            T[0] = 1.5f - 0.5f * W[0];
            T[1] = -0.5f * W[1];
            T[2] = -0.5f * W[2];
            T[3] = 1.5f - 0.5f * W[3];
            T[4] = -0.5f * W[4];
            T[5] = 1.5f - 0.5f * W[5];
            symmul(Y, T, Yn);
            symmul(T, Z, Zn);
            #pragma unroll
            for (int i = 0; i < 6; ++i) { Y[i] = Yn[i]; Z[i] = Zn[i]; }
        }

        const float sc = 1.0f / sqrtf(tr);        // B^{-1/2} = Z / sqrt(tr)
        #pragma unroll
        for (int i = 0; i < 6; ++i) sm[tid][3 + i] = Z[i] * sc;
    }
    __syncthreads();

    // ---- Phase 3: broadcast {m, M}, transform, store ----
    if (valid) {
        const float m0  = sm[grp][0], m1 = sm[grp][1], m2 = sm[grp][2];
        const float M00 = sm[grp][3], M01 = sm[grp][4], M02 = sm[grp][5];
        const float M11 = sm[grp][6], M12 = sm[grp][7], M22 = sm[grp][8];

        #pragma unroll
        for (int j = 0; j < 2; ++j) {
            const f4 wv = *(const f4*)(wptr + j * 128 + coff);
            const f4 a  = x[0][j];
            const f4 b  = x[1][j];
            const f4 c  = x[2][j];
            f4 r0, r1, r2;
            #pragma unroll
            for (int k = 0; k < 4; ++k) {
                const float a0 = a[k] - m0;
                const float a1 = b[k] - m1;
                const float a2 = c[k] - m2;
                r0[k] = (M00 * a0 + M01 * a1 + M02 * a2) * wv[k];
                r1[k] = (M01 * a0 + M11 * a1 + M12 * a2) * wv[k];
                r2[k] = (M02 * a0 + M12 * a1 + M22 * a2) * wv[k];
            }
            __builtin_nontemporal_store(r0, (f4*)(out + base + 0 * kD + j * 128 + coff));
            __builtin_nontemporal_store(r1, (f4*)(out + base + 1 * kD + j * 128 + coff));
            __builtin_nontemporal_store(r2, (f4*)(out + base + 2 * kD + j * 128 + coff));
        }
    }
}

}  // namespace

extern "C" void kernel_launch(void* const* d_in, const int* in_sizes, int n_in,
                              void* d_out, int out_size, void* d_ws, size_t ws_size,
                              hipStream_t stream) {
    (void)n_in; (void)d_ws; (void)ws_size; (void)out_size;
    const float* in   = (const float*)d_in[0];
    const float* wght = (const float*)d_in[1];
    float* out = (float*)d_out;

    const int nrows = in_sizes[0] / (3 * kD);      // 65536
    const int blocks = (nrows + kRowsPerBlock - 1) / kRowsPerBlock;

    eqln_kernel<<<blocks, 256, 0, stream>>>(in, wght, out, nrows);
}